// Round 7
// baseline (663.664 us; speedup 1.0000x reference)
//
#include <hip/hip_runtime.h>
#include <stdint.h>

#define NROWS 8192
#define DDIM  128
#define PPART 16
#define BROWS 256                        // rows per block = 8 waves * 32
#define NITER 8                          // 8 stages of 64 B-rows = 512-col partition
#define LOG2E_X100 144.26950408889634f   // 100 / ln(2)
#define LN2F       0.6931471805599453f

typedef __bf16 bf16x8 __attribute__((ext_vector_type(8)));
typedef float  f32x4  __attribute__((ext_vector_type(4)));

__device__ __forceinline__ unsigned short f2bf_rne(float f) {
    union { float f; uint32_t u; } v; v.f = f;
    uint32_t r = (v.u + 0x7FFFu + ((v.u >> 16) & 1u)) >> 16;
    return (unsigned short)r;
}

// async global->LDS, 16B per lane; lds dest = (uniform base) + lane*16
__device__ __forceinline__ void async16(const unsigned short* g, unsigned char* l) {
    __builtin_amdgcn_global_load_lds(
        (const __attribute__((address_space(1))) unsigned int*)g,
        (__attribute__((address_space(3))) unsigned int*)l, 16, 0, 0);
}

// Kernel 1: fp32 -> bf16. ts pre-scaled by 100*log2(e) (base-2 softmax space).
// Also zeroes the cross-block bookkeeping (re-poisoned to 0xAA every launch).
__global__ void convert_kernel(const float* __restrict__ ts, const float* __restrict__ nt,
                               unsigned short* __restrict__ ts_bf,
                               unsigned short* __restrict__ nt_bf,
                               float* __restrict__ acc, int* __restrict__ ctrl) {
    const int nvec = (NROWS * DDIM) / 4;
    int tid = blockIdx.x * blockDim.x + threadIdx.x;
    bool isNT = tid >= nvec;
    int i = isNT ? (tid - nvec) : tid;
    const float4 v = ((const float4*)(isNT ? nt : ts))[i];
    float sc = isNT ? 1.0f : LOG2E_X100;
    ushort4 o;
    o.x = f2bf_rne(v.x * sc); o.y = f2bf_rne(v.y * sc);
    o.z = f2bf_rne(v.z * sc); o.w = f2bf_rne(v.w * sc);
    ((ushort4*)(isNT ? nt_bf : ts_bf))[i] = o;
    if (tid < 65) ctrl[tid] = 0;          // ctrl[0..63] = per-(dir,bx) counters, ctrl[64] = ticket
    if (tid == 65) *acc = 0.0f;
}

// DMA one 64-row stage (16 KB) into LDS in OPERAND ORDER, split across 8 waves.
// Segment u = (slot<<2)|kc holds the lane-contiguous fragment for (slot,kc):
// LDS[u*1024 + lane*16] = B[slot*16 + (lane&15)][ (kc*4 + (lane>>4))*8 .. +8 ].
// Both DMA writes and compute reads are linear lane*16 => conflict-free.
__device__ __forceinline__ void dma_stage(const unsigned short* g, unsigned char* l,
                                          int lane, int wv) {
#pragma unroll
    for (int k = 0; k < 2; ++k) {
        int u    = wv * 2 + k;                 // 0..15
        int slot = u >> 2, kc = u & 3;
        int row  = slot * 16 + (lane & 15);    // stage row 0..63
        int ch   = kc * 4 + (lane >> 4);       // 16B chunk 0..15 within the row
        async16(g + row * 128 + ch * 8, l + u * 1024);
    }
}

// Kernel 2: per-row online-softmax stats, base-2 space. 8 waves/block; each
// wave = 32 rows (2 strips). 64 B-rows/stage in double-buffered LDS (operand-
// ordered, conflict-free, immediate-offset ds_read_b128). Fused merge at end.
// grid = (NROWS/BROWS, PPART, 2).
__global__ __launch_bounds__(512, 4) void rowstats_kernel(
        const unsigned short* __restrict__ ts_bf,
        const unsigned short* __restrict__ nt_bf,
        float* __restrict__ pm, float* __restrict__ ps, float* __restrict__ pd,
        float* __restrict__ acc, int* __restrict__ ctrl, float* __restrict__ out) {
    __shared__ unsigned char smem[2 * 16384];

    const int lane = threadIdx.x & 63;
    const int wv   = threadIdx.x >> 6;         // 0..7
    const int c    = lane & 15;
    const int quad = lane >> 4;
    const int bx   = blockIdx.x;               // 0..31
    const int part = blockIdx.y;               // 0..15
    const int dir  = blockIdx.z;
    const int rows0 = bx * BROWS + wv * 32;

    const unsigned short* A = dir ? nt_bf : ts_bf;
    const unsigned short* B = dir ? ts_bf : nt_bf;

    // A fragments: this wave's 32 rows (2 strips), in regs (32 VGPRs).
    bf16x8 a[2][4];
#pragma unroll
    for (int s = 0; s < 2; ++s) {
        const unsigned short* abase = A + (rows0 + s * 16 + c) * DDIM + quad * 8;
#pragma unroll
        for (int kc = 0; kc < 4; ++kc)
            a[s][kc] = *(const bf16x8*)(abase + kc * 32);
    }

    float m[2][4], ss[2][4], dg[2][4];
#pragma unroll
    for (int s = 0; s < 2; ++s)
#pragma unroll
        for (int r = 0; r < 4; ++r) { m[s][r] = -INFINITY; ss[s][r] = 0.0f; dg[s][r] = 0.0f; }

    // Diagonal bookkeeping (PPART=16: 32 col-tiles/partition, 4 tiles/stage).
    // Wave's diag tiles g = bx*16 + 2wv + s live in partition bx>>1,
    // stage (bx&1)*4 + (wv>>1), slots (wv&1)*2 + s.
    const bool havePart = (part == (bx >> 1));
    const int  t_d = (bx & 1) * 4 + (wv >> 1);
    const int  l0  = (wv & 1) * 2;

    const unsigned short* bwalk = B + part * (NROWS / PPART) * DDIM;

    dma_stage(bwalk, smem, lane, wv);
    __syncthreads();

    for (int t = 0; t < NITER; ++t) {
        if (t + 1 < NITER)
            dma_stage(bwalk + (t + 1) * 64 * DDIM, smem + ((t + 1) & 1) * 16384, lane, wv);

        const unsigned char* buf = smem + (t & 1) * 16384 + lane * 16;

        f32x4 av[4][2];
#pragma unroll
        for (int l = 0; l < 4; ++l)
#pragma unroll
            for (int s = 0; s < 2; ++s) av[l][s] = (f32x4){0.f, 0.f, 0.f, 0.f};

#pragma unroll
        for (int kc = 0; kc < 4; ++kc) {
            bf16x8 b0 = *(const bf16x8*)(buf + kc * 1024);
            bf16x8 b1 = *(const bf16x8*)(buf + kc * 1024 + 4096);
            bf16x8 b2 = *(const bf16x8*)(buf + kc * 1024 + 8192);
            bf16x8 b3 = *(const bf16x8*)(buf + kc * 1024 + 12288);
            av[0][0] = __builtin_amdgcn_mfma_f32_16x16x32_bf16(a[0][kc], b0, av[0][0], 0, 0, 0);
            av[0][1] = __builtin_amdgcn_mfma_f32_16x16x32_bf16(a[1][kc], b0, av[0][1], 0, 0, 0);
            av[1][0] = __builtin_amdgcn_mfma_f32_16x16x32_bf16(a[0][kc], b1, av[1][0], 0, 0, 0);
            av[1][1] = __builtin_amdgcn_mfma_f32_16x16x32_bf16(a[1][kc], b1, av[1][1], 0, 0, 0);
            av[2][0] = __builtin_amdgcn_mfma_f32_16x16x32_bf16(a[0][kc], b2, av[2][0], 0, 0, 0);
            av[2][1] = __builtin_amdgcn_mfma_f32_16x16x32_bf16(a[1][kc], b2, av[2][1], 0, 0, 0);
            av[3][0] = __builtin_amdgcn_mfma_f32_16x16x32_bf16(a[0][kc], b3, av[3][0], 0, 0, 0);
            av[3][1] = __builtin_amdgcn_mfma_f32_16x16x32_bf16(a[1][kc], b3, av[3][1], 0, 0, 0);
        }

        const bool pd_ = havePart && (t == t_d);   // wave-uniform, true for 1 stage
#pragma unroll
        for (int s = 0; s < 2; ++s) {
#pragma unroll
            for (int r = 0; r < 4; ++r) {
                float x0 = av[0][s][r], x1 = av[1][s][r];
                float x2 = av[2][s][r], x3 = av[3][s][r];
                if (pd_) {
                    const int dslot = l0 + s;       // wave-uniform 0..3
                    bool onDiag = (c == quad * 4 + r);
                    float xv = dslot == 0 ? x0 : dslot == 1 ? x1 : dslot == 2 ? x2 : x3;
                    if (onDiag) dg[s][r] += xv;
                    float rep = onDiag ? xv : -1.0e30f;
                    if (dslot == 0) x0 = rep; else if (dslot == 1) x1 = rep;
                    else if (dslot == 2) x2 = rep; else x3 = rep;
                }
                float mn = fmaxf(fmaxf(fmaxf(x0, x1), fmaxf(x2, x3)), m[s][r]);
                float e  = __builtin_amdgcn_exp2f(m[s][r] - mn);
                float es = (__builtin_amdgcn_exp2f(x0 - mn) + __builtin_amdgcn_exp2f(x1 - mn))
                         + (__builtin_amdgcn_exp2f(x2 - mn) + __builtin_amdgcn_exp2f(x3 - mn));
                ss[s][r] = fmaf(ss[s][r], e, es);
                m[s][r] = mn;
            }
        }
        __syncthreads();
    }

    // Epilogue: 16-lane combine per quad. Max-reduce, single rescale, sum-reduce.
#pragma unroll
    for (int s = 0; s < 2; ++s) {
#pragma unroll
        for (int r = 0; r < 4; ++r) {
            float mm = m[s][r];
#pragma unroll
            for (int off = 1; off < 16; off <<= 1)
                mm = fmaxf(mm, __shfl_xor(mm, off, 64));
            float sv = ss[s][r] * __builtin_amdgcn_exp2f(m[s][r] - mm);
            float dd = dg[s][r];
#pragma unroll
            for (int off = 1; off < 16; off <<= 1) {
                sv += __shfl_xor(sv, off, 64);
                dd += __shfl_xor(dd, off, 64);
            }
            if (c == 0) {
                int row = rows0 + s * 16 + quad * 4 + r;
                int idx = (dir * NROWS + row) * PPART + part;
                pm[idx] = mm; ps[idx] = sv; pd[idx] = dd;
            }
        }
    }

    // Fused merge: last of the 16 part-blocks for this (dir,bx) merges its 256 rows.
    __threadfence();                               // make partials device-visible
    __shared__ int sflag;
    __shared__ float wsum[8];
    if (threadIdx.x == 0) {
        int old = atomicAdd(&ctrl[dir * 32 + bx], 1);
        sflag = (old == PPART - 1) ? 1 : 0;
    }
    __syncthreads();
    if (sflag) {
        __threadfence();
        float lsm = 0.0f;
        if (threadIdx.x < BROWS) {
            int row = bx * BROWS + threadIdx.x;
            int idx = (dir * NROWS + row) * PPART;
            float mt = -INFINITY;
#pragma unroll
            for (int p = 0; p < PPART; ++p) mt = fmaxf(mt, pm[idx + p]);
            float st = 0.0f, dt = 0.0f;
#pragma unroll
            for (int p = 0; p < PPART; ++p) {
                st += ps[idx + p] * __builtin_amdgcn_exp2f(pm[idx + p] - mt);
                dt += pd[idx + p];
            }
            lsm = dt - mt - __builtin_amdgcn_logf(st);   // base-2
        }
        float v = lsm;
#pragma unroll
        for (int off = 32; off; off >>= 1) v += __shfl_down(v, off, 64);
        if (lane == 0) wsum[wv] = v;
        __syncthreads();
        if (threadIdx.x == 0) {
            float bsum = 0.0f;
#pragma unroll
            for (int w = 0; w < 8; ++w) bsum += wsum[w];
            atomicAdd(acc, bsum);
            __threadfence();
            int old = atomicAdd(&ctrl[64], 1);
            if (old == 63) {                        // all 64 merge-groups done
                __threadfence();
                float tot = atomicAdd(acc, 0.0f);   // coherent read
                float t = -(tot * LN2F) / (2.0f * NROWS);
                if (!isfinite(t)) t = 0.0f;
                out[0] = t;
            }
        }
    }
}

extern "C" void kernel_launch(void* const* d_in, const int* in_sizes, int n_in,
                              void* d_out, int out_size, void* d_ws, size_t ws_size,
                              hipStream_t stream) {
    const float* ts = (const float*)d_in[0];
    const float* nt = (const float*)d_in[1];
    float* out = (float*)d_out;

    unsigned short* ts_bf = (unsigned short*)d_ws;                 // 2 MB
    unsigned short* nt_bf = ts_bf + NROWS * DDIM;                  // 2 MB
    float* pm = (float*)(nt_bf + NROWS * DDIM);                    // 1 MB
    float* ps = pm + 2 * NROWS * PPART;                            // 1 MB
    float* pd = ps + 2 * NROWS * PPART;                            // 1 MB
    float* acc = pd + 2 * NROWS * PPART;                           // 4 B
    int* ctrl = (int*)(acc + 1);                                   // 65 ints

    convert_kernel<<<2048, 256, 0, stream>>>(ts, nt, ts_bf, nt_bf, acc, ctrl);
    rowstats_kernel<<<dim3(NROWS / BROWS, PPART, 2), 512, 0, stream>>>(
        ts_bf, nt_bf, pm, ps, pd, acc, ctrl, out);
}

// Round 8
// 107.405 us; speedup vs baseline: 6.1791x; 6.1791x over previous
//
#include <hip/hip_runtime.h>
#include <stdint.h>

#define NROWS 8192
#define DDIM  128
#define PPART 8
#define BROWS 256                        // rows per block = 8 waves * 32
#define NITER 16                         // 16 stages of 64 B-rows = 1024-col partition
#define LOG2E_X100 144.26950408889634f   // 100 / ln(2)
#define LN2F       0.6931471805599453f

typedef __bf16 bf16x8 __attribute__((ext_vector_type(8)));
typedef float  f32x4  __attribute__((ext_vector_type(4)));
typedef unsigned short u16x8 __attribute__((ext_vector_type(8)));

// Fragment-major (F) layout: for strip g (16 rows), k-chunk kc (32 cols):
//   1 KB block at byte offset (g*4+kc)*1024; lane L=(quad*16+c) piece at L*16,
//   holding row (g*16+c), bytes [(kc*4+quad)*16 .. +16).
// Both DMA (global->LDS) and ds_read then run at linear lane*16 — coalesced
// and bank-conflict-free — with no per-read address math (imm offsets).

__device__ __forceinline__ unsigned short f2bf_rne(float f) {
    union { float f; uint32_t u; } v; v.f = f;
    uint32_t r = (v.u + 0x7FFFu + ((v.u >> 16) & 1u)) >> 16;
    return (unsigned short)r;
}

// async global->LDS, 16B per lane; lds dest = (uniform base) + lane*16
__device__ __forceinline__ void async16(const unsigned short* g, unsigned char* l) {
    __builtin_amdgcn_global_load_lds(
        (const __attribute__((address_space(1))) unsigned int*)g,
        (__attribute__((address_space(3))) unsigned int*)l, 16, 0, 0);
}

// Kernel 1: fp32 -> bf16 into FRAGMENT-MAJOR layout. ts pre-scaled by
// 100*log2(e) (base-2 softmax space). One thread = one 16B output chunk.
__global__ void convert_kernel(const float* __restrict__ ts, const float* __restrict__ nt,
                               unsigned short* __restrict__ ts_bf,
                               unsigned short* __restrict__ nt_bf,
                               float* __restrict__ acc, int* __restrict__ ticket) {
    const int nchunk = (NROWS * DDIM) / 8;          // 131072 chunks per matrix
    int tid = blockIdx.x * blockDim.x + threadIdx.x; // 0 .. 2*nchunk-1
    bool isNT = tid >= nchunk;
    int i = isNT ? (tid - nchunk) : tid;
    const float4* src = (const float4*)(isNT ? nt : ts) + i * 2;
    float4 v0 = src[0], v1 = src[1];
    float sc = isNT ? 1.0f : LOG2E_X100;
    u16x8 o;
    o[0] = f2bf_rne(v0.x * sc); o[1] = f2bf_rne(v0.y * sc);
    o[2] = f2bf_rne(v0.z * sc); o[3] = f2bf_rne(v0.w * sc);
    o[4] = f2bf_rne(v1.x * sc); o[5] = f2bf_rne(v1.y * sc);
    o[6] = f2bf_rne(v1.z * sc); o[7] = f2bf_rne(v1.w * sc);
    int row = i >> 4, chunk = i & 15;               // row 0..8191, 16B-chunk 0..15
    int g = row >> 4, c = row & 15;
    int kc = chunk >> 2, quad = chunk & 3;
    int off16 = (g * 4 + kc) * 64 + quad * 16 + c;  // in 16B units
    ((u16x8*)(isNT ? nt_bf : ts_bf))[off16] = o;
    if (tid == 0) { *acc = 0.0f; *ticket = 0; }
}

// DMA one 64-row stage (16 KB, contiguous in F layout) into LDS, split across
// 8 waves (2 x 1KB instructions each). Fully coalesced; LDS lands operand-ordered.
__device__ __forceinline__ void dma_stage(const unsigned short* g, unsigned char* l,
                                          int lane, int wv) {
#pragma unroll
    for (int k = 0; k < 2; ++k) {
        int u = wv * 2 + k;                        // block 0..15 of the stage
        async16(g + u * 512 + lane * 8, l + u * 1024);
    }
}

// Kernel 2: per-row online-softmax stats, base-2 space. 8 waves/block; each
// wave = 32 rows (2 strips). 64 B-rows/stage double-buffered in LDS
// (fragment-major: conflict-free lane-linear ds_read_b128, imm offsets).
// grid = (NROWS/BROWS, PPART, 2).
__global__ __launch_bounds__(512, 4) void rowstats_kernel(
        const unsigned short* __restrict__ ts_bf,
        const unsigned short* __restrict__ nt_bf,
        float* __restrict__ pm, float* __restrict__ ps, float* __restrict__ pd) {
    __shared__ unsigned char smem[2 * 16384];

    const int lane = threadIdx.x & 63;
    const int wv   = threadIdx.x >> 6;         // 0..7
    const int c    = lane & 15;
    const int quad = lane >> 4;
    const int bx   = blockIdx.x;               // 0..31
    const int part = blockIdx.y;               // 0..7
    const int dir  = blockIdx.z;
    const int rows0 = bx * BROWS + wv * 32;

    const unsigned short* A = dir ? nt_bf : ts_bf;   // fragment-major
    const unsigned short* B = dir ? ts_bf : nt_bf;   // fragment-major

    // A fragments: this wave's strips G0, G0+1; lane-linear coalesced loads.
    const int G0 = bx * 16 + wv * 2;
    bf16x8 a[2][4];
#pragma unroll
    for (int s = 0; s < 2; ++s)
#pragma unroll
        for (int kc = 0; kc < 4; ++kc)
            a[s][kc] = *(const bf16x8*)(A + ((G0 + s) * 4 + kc) * 512 + lane * 8);

    float m[2][4], ss[2][4], dg[2][4];
#pragma unroll
    for (int s = 0; s < 2; ++s)
#pragma unroll
        for (int r = 0; r < 4; ++r) { m[s][r] = -INFINITY; ss[s][r] = 0.0f; dg[s][r] = 0.0f; }

    // Diagonal bookkeeping (same algebra as R5): diag strips of this wave live
    // in partition bx>>2, stage (bx&3)*4+(wv>>1), slots (wv&1)*2+s.
    const bool havePart = (part == (bx >> 2));
    const int  t_d = (bx & 3) * 4 + (wv >> 1);
    const int  l0  = (wv & 1) * 2;

    // Partition B base: strip part*64, i.e. ushort offset part*64*4*512.
    const unsigned short* bwalk = B + part * 64 * 2048;

    dma_stage(bwalk, smem, lane, wv);
    __syncthreads();

    for (int t = 0; t < NITER; ++t) {
        if (t + 1 < NITER)
            dma_stage(bwalk + (t + 1) * 8192, smem + ((t + 1) & 1) * 16384, lane, wv);

        const unsigned char* buf = smem + (t & 1) * 16384 + lane * 16;

        f32x4 av[4][2];
#pragma unroll
        for (int l = 0; l < 4; ++l)
#pragma unroll
            for (int s = 0; s < 2; ++s) av[l][s] = (f32x4){0.f, 0.f, 0.f, 0.f};

#pragma unroll
        for (int kc = 0; kc < 4; ++kc) {
            bf16x8 b0 = *(const bf16x8*)(buf + kc * 1024);
            bf16x8 b1 = *(const bf16x8*)(buf + kc * 1024 + 4096);
            bf16x8 b2 = *(const bf16x8*)(buf + kc * 1024 + 8192);
            bf16x8 b3 = *(const bf16x8*)(buf + kc * 1024 + 12288);
            av[0][0] = __builtin_amdgcn_mfma_f32_16x16x32_bf16(a[0][kc], b0, av[0][0], 0, 0, 0);
            av[0][1] = __builtin_amdgcn_mfma_f32_16x16x32_bf16(a[1][kc], b0, av[0][1], 0, 0, 0);
            av[1][0] = __builtin_amdgcn_mfma_f32_16x16x32_bf16(a[0][kc], b1, av[1][0], 0, 0, 0);
            av[1][1] = __builtin_amdgcn_mfma_f32_16x16x32_bf16(a[1][kc], b1, av[1][1], 0, 0, 0);
            av[2][0] = __builtin_amdgcn_mfma_f32_16x16x32_bf16(a[0][kc], b2, av[2][0], 0, 0, 0);
            av[2][1] = __builtin_amdgcn_mfma_f32_16x16x32_bf16(a[1][kc], b2, av[2][1], 0, 0, 0);
            av[3][0] = __builtin_amdgcn_mfma_f32_16x16x32_bf16(a[0][kc], b3, av[3][0], 0, 0, 0);
            av[3][1] = __builtin_amdgcn_mfma_f32_16x16x32_bf16(a[1][kc], b3, av[3][1], 0, 0, 0);
        }

        const bool pd_ = havePart && (t == t_d);   // wave-uniform, true for 1 stage
#pragma unroll
        for (int s = 0; s < 2; ++s) {
#pragma unroll
            for (int r = 0; r < 4; ++r) {
                float x0 = av[0][s][r], x1 = av[1][s][r];
                float x2 = av[2][s][r], x3 = av[3][s][r];
                if (pd_) {
                    const int dslot = l0 + s;       // wave-uniform 0..3
                    bool onDiag = (c == quad * 4 + r);
                    float xv = dslot == 0 ? x0 : dslot == 1 ? x1 : dslot == 2 ? x2 : x3;
                    if (onDiag) dg[s][r] += xv;
                    float rep = onDiag ? xv : -1.0e30f;
                    if (dslot == 0) x0 = rep; else if (dslot == 1) x1 = rep;
                    else if (dslot == 2) x2 = rep; else x3 = rep;
                }
                float mn = fmaxf(fmaxf(fmaxf(x0, x1), fmaxf(x2, x3)), m[s][r]);
                float e  = __builtin_amdgcn_exp2f(m[s][r] - mn);
                float es = (__builtin_amdgcn_exp2f(x0 - mn) + __builtin_amdgcn_exp2f(x1 - mn))
                         + (__builtin_amdgcn_exp2f(x2 - mn) + __builtin_amdgcn_exp2f(x3 - mn));
                ss[s][r] = fmaf(ss[s][r], e, es);
                m[s][r] = mn;
            }
        }
        __syncthreads();
    }

    // Epilogue: 16-lane combine per quad. Max-reduce, single rescale, sum-reduce.
#pragma unroll
    for (int s = 0; s < 2; ++s) {
#pragma unroll
        for (int r = 0; r < 4; ++r) {
            float mm = m[s][r];
#pragma unroll
            for (int off = 1; off < 16; off <<= 1)
                mm = fmaxf(mm, __shfl_xor(mm, off, 64));
            float sv = ss[s][r] * __builtin_amdgcn_exp2f(m[s][r] - mm);
            float dd = dg[s][r];
#pragma unroll
            for (int off = 1; off < 16; off <<= 1) {
                sv += __shfl_xor(sv, off, 64);
                dd += __shfl_xor(dd, off, 64);
            }
            if (c == 0) {
                int row = rows0 + s * 16 + quad * 4 + r;
                int idx = (dir * NROWS + row) * PPART + part;
                pm[idx] = mm; ps[idx] = sv; pd[idx] = dd;
            }
        }
    }
}

// Kernel 3: merge partitions per (dir,row), block-reduce, atomicAdd;
// last block finalizes the scalar output (base-2 -> natural via ln2).
__global__ void merge_kernel(const float* __restrict__ pm, const float* __restrict__ ps,
                             const float* __restrict__ pd, float* __restrict__ acc,
                             int* __restrict__ ticket, float* __restrict__ out) {
    int tid = blockIdx.x * blockDim.x + threadIdx.x;  // 0 .. 2*NROWS-1
    const float* pmr = pm + tid * PPART;
    const float* psr = ps + tid * PPART;
    const float* pdr = pd + tid * PPART;
    float mt = -INFINITY;
#pragma unroll
    for (int p = 0; p < PPART; ++p) mt = fmaxf(mt, pmr[p]);
    float st = 0.0f, dt = 0.0f;
#pragma unroll
    for (int p = 0; p < PPART; ++p) {
        st += psr[p] * __builtin_amdgcn_exp2f(pmr[p] - mt);
        dt += pdr[p];
    }
    float lsm = dt - mt - __builtin_amdgcn_logf(st);   // base-2 log-softmax at diagonal

    float v = lsm;
#pragma unroll
    for (int off = 32; off; off >>= 1) v += __shfl_down(v, off, 64);
    __shared__ float wsum[4];
    if ((threadIdx.x & 63) == 0) wsum[threadIdx.x >> 6] = v;
    __syncthreads();
    if (threadIdx.x == 0) {
        atomicAdd(acc, wsum[0] + wsum[1] + wsum[2] + wsum[3]);
        __threadfence();
        int old = atomicAdd(ticket, 1);
        if (old == (int)gridDim.x - 1) {
            __threadfence();
            float tot = atomicAdd(acc, 0.0f);   // coherent read of final sum
            float t = -(tot * LN2F) / (2.0f * NROWS);
            if (!isfinite(t)) t = 0.0f;
            out[0] = t;
        }
    }
}

extern "C" void kernel_launch(void* const* d_in, const int* in_sizes, int n_in,
                              void* d_out, int out_size, void* d_ws, size_t ws_size,
                              hipStream_t stream) {
    const float* ts = (const float*)d_in[0];
    const float* nt = (const float*)d_in[1];
    float* out = (float*)d_out;

    unsigned short* ts_bf = (unsigned short*)d_ws;                 // 2 MB (fragment-major)
    unsigned short* nt_bf = ts_bf + NROWS * DDIM;                  // 2 MB (fragment-major)
    float* pm = (float*)(nt_bf + NROWS * DDIM);                    // 512 KB
    float* ps = pm + 2 * NROWS * PPART;                            // 512 KB
    float* pd = ps + 2 * NROWS * PPART;                            // 512 KB
    float* acc = pd + 2 * NROWS * PPART;                           // 4 B
    int* ticket = (int*)(acc + 1);                                 // 4 B

    convert_kernel<<<1024, 256, 0, stream>>>(ts, nt, ts_bf, nt_bf, acc, ticket);
    rowstats_kernel<<<dim3(NROWS / BROWS, PPART, 2), 512, 0, stream>>>(ts_bf, nt_bf, pm, ps, pd);
    merge_kernel<<<(2 * NROWS) / 256, 256, 0, stream>>>(pm, ps, pd, acc, ticket, out);
}